// Round 1
// baseline (2782.956 us; speedup 1.0000x reference)
//
#include <hip/hip_runtime.h>

#define THREADS 256

// Workspace layout (bytes from base), N = #nodes:
//   deg  : [0, 4N)        u32
//   dinv : [4N, 8N)       f32
//   xs   : [8N, 24N)      f32 x4 per node (x * dinv)
//   agg  : [24N, 40N)     f32 x4 per node (layer-1 accumulator, init = xs self-loop)
//   ps   : [40N, 48N)     f32 x2 per node (p * dinv)
//   aggp : [48N, 56N)     f32 x2 per node (layer-2 accumulator, init = ps)
//   flag : [56N, 56N+4)   int (1 => edge_index stored as int64)

// Detect whether edge_index is int64 (high dwords all zero) or int32.
__global__ void detect_i64(const int* __restrict__ ei, int* __restrict__ flag) {
    if (blockIdx.x == 0 && threadIdx.x == 0) {
        int allzero = 1;
        for (int k = 0; k < 64; ++k) {
            if (ei[2 * k + 1] != 0) { allzero = 0; break; }
        }
        *flag = allzero;
    }
}

__device__ __forceinline__ int edge_idx(const int* __restrict__ ei, long long pos, int is64) {
    // pos is the logical flat index into the [2,E] int array.
    return is64 ? ei[2 * pos] : ei[(size_t)pos];
}

__global__ void count_deg(const int* __restrict__ ei, int E, int is64_hint,
                          const int* __restrict__ flagp, unsigned int* __restrict__ deg) {
    int is64 = *flagp;
    int e = blockIdx.x * blockDim.x + threadIdx.x;
    if (e >= E) return;
    int d = edge_idx(ei, (long long)E + e, is64);
    atomicAdd(&deg[d], 1u);
}

__global__ void node_prep(const float4* __restrict__ x, const unsigned int* __restrict__ deg,
                          float* __restrict__ dinv, float4* __restrict__ xs,
                          float4* __restrict__ agg, int N) {
    int i = blockIdx.x * blockDim.x + threadIdx.x;
    if (i >= N) return;
    float di = rsqrtf((float)(deg[i] + 1u));
    dinv[i] = di;
    float4 v = x[i];
    v.x *= di; v.y *= di; v.z *= di; v.w *= di;
    xs[i] = v;
    agg[i] = v;   // self-loop contribution
}

__global__ void edge_agg4(const int* __restrict__ ei, int E, const int* __restrict__ flagp,
                          const float4* __restrict__ xs, float* __restrict__ agg) {
    int is64 = *flagp;
    int e = blockIdx.x * blockDim.x + threadIdx.x;
    if (e >= E) return;
    int s = edge_idx(ei, e, is64);
    int d = edge_idx(ei, (long long)E + e, is64);
    float4 v = xs[s];
    atomicAdd(&agg[4 * (size_t)d + 0], v.x);
    atomicAdd(&agg[4 * (size_t)d + 1], v.y);
    atomicAdd(&agg[4 * (size_t)d + 2], v.z);
    atomicAdd(&agg[4 * (size_t)d + 3], v.w);
}

// Fused: v = dinv*agg ; h = relu(v@W1 + b1) ; p = h@W2 ; ps = p*dinv ; aggp init.
__global__ __launch_bounds__(THREADS) void node_mid(
    const float4* __restrict__ agg, const float* __restrict__ dinv,
    const float* __restrict__ W1, const float* __restrict__ b1,
    const float* __restrict__ W2,
    float2* __restrict__ ps, float2* __restrict__ aggp, int N) {
    __shared__ float sW1[256];  // W1[4][64] row-major
    __shared__ float sb1[64];
    __shared__ float sW2[128];  // W2[64][2] row-major
    int t = threadIdx.x;
    sW1[t] = W1[t];
    if (t < 64) sb1[t] = b1[t];
    if (t < 128) sW2[t] = W2[t];
    __syncthreads();
    int i = blockIdx.x * blockDim.x + t;
    if (i >= N) return;
    float di = dinv[i];
    float4 v = agg[i];
    v.x *= di; v.y *= di; v.z *= di; v.w *= di;
    float p0 = 0.0f, p1 = 0.0f;
#pragma unroll
    for (int j = 0; j < 64; ++j) {
        float h = fmaf(v.x, sW1[j],
                  fmaf(v.y, sW1[64 + j],
                  fmaf(v.z, sW1[128 + j],
                  fmaf(v.w, sW1[192 + j], sb1[j]))));
        h = fmaxf(h, 0.0f);
        p0 = fmaf(h, sW2[2 * j + 0], p0);
        p1 = fmaf(h, sW2[2 * j + 1], p1);
    }
    float2 r;
    r.x = p0 * di;
    r.y = p1 * di;
    ps[i] = r;
    aggp[i] = r;  // self-loop contribution
}

__global__ void edge_agg2(const int* __restrict__ ei, int E, const int* __restrict__ flagp,
                          const float2* __restrict__ ps, float* __restrict__ aggp) {
    int is64 = *flagp;
    int e = blockIdx.x * blockDim.x + threadIdx.x;
    if (e >= E) return;
    int s = edge_idx(ei, e, is64);
    int d = edge_idx(ei, (long long)E + e, is64);
    float2 v = ps[s];
    atomicAdd(&aggp[2 * (size_t)d + 0], v.x);
    atomicAdd(&aggp[2 * (size_t)d + 1], v.y);
}

__global__ void node_final(const float2* __restrict__ aggp, const float* __restrict__ dinv,
                           const float* __restrict__ b2, float2* __restrict__ out, int N) {
    int i = blockIdx.x * blockDim.x + threadIdx.x;
    if (i >= N) return;
    float di = dinv[i];
    float2 a = aggp[i];
    float2 r;
    r.x = fmaf(a.x, di, b2[0]);
    r.y = fmaf(a.y, di, b2[1]);
    out[i] = r;
}

extern "C" void kernel_launch(void* const* d_in, const int* in_sizes, int n_in,
                              void* d_out, int out_size, void* d_ws, size_t ws_size,
                              hipStream_t stream) {
    const float* x  = (const float*)d_in[0];
    const int*   ei = (const int*)d_in[1];
    const float* W1 = (const float*)d_in[2];
    const float* b1 = (const float*)d_in[3];
    const float* W2 = (const float*)d_in[4];
    const float* b2 = (const float*)d_in[5];

    const int N = in_sizes[0] / 4;
    const int E = in_sizes[1] / 2;

    char* ws = (char*)d_ws;
    unsigned int* deg  = (unsigned int*)(ws);
    float*        dinv = (float*)(ws + (size_t)N * 4);
    float*        xs   = (float*)(ws + (size_t)N * 8);
    float*        agg  = (float*)(ws + (size_t)N * 24);
    float*        ps   = (float*)(ws + (size_t)N * 40);
    float*        aggp = (float*)(ws + (size_t)N * 48);
    int*          flag = (int*)(ws + (size_t)N * 56);

    hipMemsetAsync(deg, 0, (size_t)N * 4, stream);
    detect_i64<<<1, 64, 0, stream>>>(ei, flag);

    const int eblocks = (E + THREADS - 1) / THREADS;
    const int nblocks = (N + THREADS - 1) / THREADS;

    count_deg<<<eblocks, THREADS, 0, stream>>>(ei, E, 0, flag, deg);
    node_prep<<<nblocks, THREADS, 0, stream>>>((const float4*)x, deg, dinv,
                                               (float4*)xs, (float4*)agg, N);
    edge_agg4<<<eblocks, THREADS, 0, stream>>>(ei, E, flag, (const float4*)xs, agg);
    node_mid<<<nblocks, THREADS, 0, stream>>>((const float4*)agg, dinv, W1, b1, W2,
                                              (float2*)ps, (float2*)aggp, N);
    edge_agg2<<<eblocks, THREADS, 0, stream>>>(ei, E, flag, (const float2*)ps, aggp);
    node_final<<<nblocks, THREADS, 0, stream>>>((const float2*)aggp, dinv, b2,
                                                (float2*)d_out, N);
}

// Round 2
// 1448.388 us; speedup vs baseline: 1.9214x; 1.9214x over previous
//
#include <hip/hip_runtime.h>

#define THREADS 256

// Workspace layout (bytes from base), N = #nodes, E = #edges:
//   head : [0, 4N)         int   (per-dst chain head, -1 = empty)
//   dinv : [4N, 8N)        f32   rsqrt(deg+1)
//   ps   : [8N, 16N)       f32x2 (p * dinv, layer-2 messages)
//   next : [16N, 16N+4E)   int   (chain links)
// Total: 16N + 4E = 16 MB + 32 MB = 48 MB  (< 56 MB known-good from R1)

// edge_index may arrive as int64 (little-endian, ids < 2^20 => odd dwords all 0)
// or int32. Uniform per-thread check of the first 8 odd dwords; if data were
// int32, P(all 8 uniformly-random ids == 0) ~ 1e-48.
__device__ __forceinline__ int detect64(const int* __restrict__ ei) {
    return (ei[1] | ei[3] | ei[5] | ei[7] | ei[9] | ei[11] | ei[13] | ei[15]) == 0;
}

__device__ __forceinline__ int load_src(const int* __restrict__ ei, int e, int is64) {
    return is64 ? ei[2 * (size_t)e] : ei[(size_t)e];
}
__device__ __forceinline__ int load_dst(const int* __restrict__ ei, int E, int e, int is64) {
    return is64 ? ei[2 * ((size_t)E + e)] : ei[(size_t)E + e];
}

// One device-atomic per edge: push e onto dst's chain.
__global__ void build_ll(const int* __restrict__ ei, int E,
                         int* __restrict__ head, int* __restrict__ next) {
    int e = blockIdx.x * blockDim.x + threadIdx.x;
    if (e >= E) return;
    int is64 = detect64(ei);
    int d = load_dst(ei, E, e, is64);
    int old = atomicExch(&head[d], e);
    next[e] = old;
}

// Chain length -> dinv = rsqrt(in-degree + 1 self-loop).
__global__ void walk_deg(const int* __restrict__ head, const int* __restrict__ next,
                         float* __restrict__ dinv, int N) {
    int i = blockIdx.x * blockDim.x + threadIdx.x;
    if (i >= N) return;
    int e = head[i];
    int cnt = 1;  // self-loop
    while (e >= 0) { cnt++; e = next[e]; }
    dinv[i] = rsqrtf((float)cnt);
}

// Layer-1 aggregate (gather via chain) fused with the 4->64->2 MLP.
// acc = x[i]*dinv[i] + sum_{e: dst=i} x[src]*dinv[src]
// v = acc*dinv[i]; h = relu(v@W1+b1); p = h@W2; ps[i] = p*dinv[i]
__global__ __launch_bounds__(THREADS) void walk_l1(
    const int* __restrict__ ei, int E,
    const int* __restrict__ head, const int* __restrict__ next,
    const float4* __restrict__ x, const float* __restrict__ dinv,
    const float* __restrict__ W1, const float* __restrict__ b1,
    const float* __restrict__ W2,
    float2* __restrict__ ps, int N) {
    __shared__ float sW1[256];  // W1[4][64] row-major
    __shared__ float sb1[64];
    __shared__ float sW2[128];  // W2[64][2] row-major
    int t = threadIdx.x;
    sW1[t] = W1[t];
    if (t < 64) sb1[t] = b1[t];
    if (t < 128) sW2[t] = W2[t];
    __syncthreads();
    int i = blockIdx.x * blockDim.x + t;
    if (i >= N) return;
    int is64 = detect64(ei);
    float di = dinv[i];
    float4 xv = x[i];
    float ax = xv.x * di, ay = xv.y * di, az = xv.z * di, aw = xv.w * di;  // self-loop
    int e = head[i];
    while (e >= 0) {
        int s = load_src(ei, e, is64);
        int en = next[e];          // issue chase load early
        float ds = dinv[s];
        float4 v = x[s];
        ax = fmaf(v.x, ds, ax);
        ay = fmaf(v.y, ds, ay);
        az = fmaf(v.z, ds, az);
        aw = fmaf(v.w, ds, aw);
        e = en;
    }
    ax *= di; ay *= di; az *= di; aw *= di;
    float p0 = 0.0f, p1 = 0.0f;
#pragma unroll
    for (int j = 0; j < 64; ++j) {
        float h = fmaf(ax, sW1[j],
                  fmaf(ay, sW1[64 + j],
                  fmaf(az, sW1[128 + j],
                  fmaf(aw, sW1[192 + j], sb1[j]))));
        h = fmaxf(h, 0.0f);
        p0 = fmaf(h, sW2[2 * j + 0], p0);
        p1 = fmaf(h, sW2[2 * j + 1], p1);
    }
    float2 r;
    r.x = p0 * di;
    r.y = p1 * di;
    ps[i] = r;
}

// Layer-2 aggregate fused with the epilogue: out[i] = dinv[i]*(ps[i]+sum ps[src]) + b2
__global__ void walk_l2(const int* __restrict__ ei, int E,
                        const int* __restrict__ head, const int* __restrict__ next,
                        const float2* __restrict__ ps, const float* __restrict__ dinv,
                        const float* __restrict__ b2,
                        float2* __restrict__ out, int N) {
    int i = blockIdx.x * blockDim.x + threadIdx.x;
    if (i >= N) return;
    int is64 = detect64(ei);
    float di = dinv[i];
    float2 acc = ps[i];  // self-loop
    int e = head[i];
    while (e >= 0) {
        int s = load_src(ei, e, is64);
        int en = next[e];
        float2 v = ps[s];
        acc.x += v.x;
        acc.y += v.y;
        e = en;
    }
    float2 r;
    r.x = fmaf(acc.x, di, b2[0]);
    r.y = fmaf(acc.y, di, b2[1]);
    out[i] = r;
}

extern "C" void kernel_launch(void* const* d_in, const int* in_sizes, int n_in,
                              void* d_out, int out_size, void* d_ws, size_t ws_size,
                              hipStream_t stream) {
    const float* x  = (const float*)d_in[0];
    const int*   ei = (const int*)d_in[1];
    const float* W1 = (const float*)d_in[2];
    const float* b1 = (const float*)d_in[3];
    const float* W2 = (const float*)d_in[4];
    const float* b2 = (const float*)d_in[5];

    const int N = in_sizes[0] / 4;
    const int E = in_sizes[1] / 2;

    char* ws = (char*)d_ws;
    int*   head = (int*)(ws);
    float* dinv = (float*)(ws + (size_t)N * 4);
    float* ps   = (float*)(ws + (size_t)N * 8);
    int*   next = (int*)(ws + (size_t)N * 16);

    hipMemsetAsync(head, 0xFF, (size_t)N * 4, stream);  // head = -1

    const int eblocks = (E + THREADS - 1) / THREADS;
    const int nblocks = (N + THREADS - 1) / THREADS;

    build_ll<<<eblocks, THREADS, 0, stream>>>(ei, E, head, next);
    walk_deg<<<nblocks, THREADS, 0, stream>>>(head, next, dinv, N);
    walk_l1<<<nblocks, THREADS, 0, stream>>>(ei, E, head, next, (const float4*)x,
                                             dinv, W1, b1, W2, (float2*)ps, N);
    walk_l2<<<nblocks, THREADS, 0, stream>>>(ei, E, head, next, (const float2*)ps,
                                             dinv, b2, (float2*)d_out, N);
}

// Round 3
// 1137.204 us; speedup vs baseline: 2.4472x; 1.2736x over previous
//
#include <hip/hip_runtime.h>

#define THREADS 256
#define K_SLOTS 12

// ---------------- shared helpers ----------------
// edge_index may arrive as int64 (little-endian, ids < 2^20 => odd dwords all 0)
// or int32. Uniform per-thread check of the first 8 odd dwords.
__device__ __forceinline__ int detect64(const int* __restrict__ ei) {
    return (ei[1] | ei[3] | ei[5] | ei[7] | ei[9] | ei[11] | ei[13] | ei[15]) == 0;
}
__device__ __forceinline__ int load_src(const int* __restrict__ ei, int e, int is64) {
    return is64 ? ei[2 * (size_t)e] : ei[(size_t)e];
}
__device__ __forceinline__ int load_dst(const int* __restrict__ ei, int E, int e, int is64) {
    return is64 ? ei[2 * ((size_t)E + e)] : ei[(size_t)E + e];
}

// =====================================================================
// Slot-CSR path (needs 92N+64 bytes of workspace)
// Layout (bytes): slots[K*N] int col-major | cnt[N] u32 | dinv[N] f32 |
//                 ovhead[N] int | ovcnt pad64 | pool[N] int2 | xs[N] f4 | ps[N] f2
// =====================================================================

__global__ void build_slots(const int* __restrict__ ei, int E, int N,
                            unsigned int* __restrict__ cnt, int* __restrict__ slots,
                            int* __restrict__ ovhead, int* __restrict__ ovcnt,
                            int2* __restrict__ pool, int poolcap) {
    int e = blockIdx.x * blockDim.x + threadIdx.x;
    if (e >= E) return;
    int is64 = detect64(ei);
    int s = load_src(ei, e, is64);
    int d = load_dst(ei, E, e, is64);
    unsigned int pos = atomicAdd(&cnt[d], 1u);
    if (pos < K_SLOTS) {
        slots[(size_t)pos * N + d] = s;   // column-major: reads coalesce per slot-row
    } else {
        int p = atomicAdd(ovcnt, 1);
        if (p < poolcap) {
            int old = atomicExch(&ovhead[d], p);
            pool[p] = make_int2(s, old);
        }
    }
}

__global__ void node_prep(const float4* __restrict__ x, const unsigned int* __restrict__ cnt,
                          float* __restrict__ dinv, float4* __restrict__ xs, int N) {
    int i = blockIdx.x * blockDim.x + threadIdx.x;
    if (i >= N) return;
    float di = rsqrtf((float)(cnt[i] + 1u));
    dinv[i] = di;
    float4 v = x[i];
    v.x *= di; v.y *= di; v.z *= di; v.w *= di;
    xs[i] = v;
}

__global__ __launch_bounds__(THREADS) void slot_l1(
    const int* __restrict__ slots, const unsigned int* __restrict__ cnt,
    const int* __restrict__ ovhead, const int2* __restrict__ pool,
    const float4* __restrict__ xs, const float* __restrict__ dinv,
    const float* __restrict__ W1, const float* __restrict__ b1,
    const float* __restrict__ W2, float2* __restrict__ ps, int N) {
    __shared__ float sW1[256];
    __shared__ float sb1[64];
    __shared__ float sW2[128];
    int t = threadIdx.x;
    sW1[t] = W1[t];
    if (t < 64) sb1[t] = b1[t];
    if (t < 128) sW2[t] = W2[t];
    __syncthreads();
    int i = blockIdx.x * blockDim.x + t;
    if (i >= N) return;
    int deg = (int)cnt[i];
    float di = dinv[i];
    float4 a = xs[i];  // self-loop
    int ns = deg < K_SLOTS ? deg : K_SLOTS;
    for (int k = 0; k < ns; ++k) {
        int s = slots[(size_t)k * N + i];
        float4 v = xs[s];
        a.x += v.x; a.y += v.y; a.z += v.z; a.w += v.w;
    }
    if (deg > K_SLOTS) {
        int p = ovhead[i];
        while (p >= 0) {
            int2 en = pool[p];
            float4 v = xs[en.x];
            a.x += v.x; a.y += v.y; a.z += v.z; a.w += v.w;
            p = en.y;
        }
    }
    a.x *= di; a.y *= di; a.z *= di; a.w *= di;
    float p0 = 0.0f, p1 = 0.0f;
#pragma unroll
    for (int j = 0; j < 64; ++j) {
        float h = fmaf(a.x, sW1[j],
                  fmaf(a.y, sW1[64 + j],
                  fmaf(a.z, sW1[128 + j],
                  fmaf(a.w, sW1[192 + j], sb1[j]))));
        h = fmaxf(h, 0.0f);
        p0 = fmaf(h, sW2[2 * j + 0], p0);
        p1 = fmaf(h, sW2[2 * j + 1], p1);
    }
    float2 r;
    r.x = p0 * di;
    r.y = p1 * di;
    ps[i] = r;
}

__global__ void slot_l2(const int* __restrict__ slots, const unsigned int* __restrict__ cnt,
                        const int* __restrict__ ovhead, const int2* __restrict__ pool,
                        const float2* __restrict__ ps, const float* __restrict__ dinv,
                        const float* __restrict__ b2, float2* __restrict__ out, int N) {
    int i = blockIdx.x * blockDim.x + threadIdx.x;
    if (i >= N) return;
    int deg = (int)cnt[i];
    float di = dinv[i];
    float2 a = ps[i];  // self-loop
    int ns = deg < K_SLOTS ? deg : K_SLOTS;
    for (int k = 0; k < ns; ++k) {
        int s = slots[(size_t)k * N + i];
        float2 v = ps[s];
        a.x += v.x; a.y += v.y;
    }
    if (deg > K_SLOTS) {
        int p = ovhead[i];
        while (p >= 0) {
            int2 en = pool[p];
            float2 v = ps[en.x];
            a.x += v.x; a.y += v.y;
            p = en.y;
        }
    }
    float2 r;
    r.x = fmaf(a.x, di, b2[0]);
    r.y = fmaf(a.y, di, b2[1]);
    out[i] = r;
}

// =====================================================================
// Fallback path (R2 linked-list, 48N bytes) — used when ws is small
// =====================================================================
__global__ void build_ll(const int* __restrict__ ei, int E,
                         int* __restrict__ head, int* __restrict__ next) {
    int e = blockIdx.x * blockDim.x + threadIdx.x;
    if (e >= E) return;
    int is64 = detect64(ei);
    int d = load_dst(ei, E, e, is64);
    int old = atomicExch(&head[d], e);
    next[e] = old;
}

__global__ void walk_deg(const int* __restrict__ head, const int* __restrict__ next,
                         float* __restrict__ dinv, int N) {
    int i = blockIdx.x * blockDim.x + threadIdx.x;
    if (i >= N) return;
    int e = head[i];
    int cnt = 1;
    while (e >= 0) { cnt++; e = next[e]; }
    dinv[i] = rsqrtf((float)cnt);
}

__global__ __launch_bounds__(THREADS) void walk_l1(
    const int* __restrict__ ei, int E,
    const int* __restrict__ head, const int* __restrict__ next,
    const float4* __restrict__ x, const float* __restrict__ dinv,
    const float* __restrict__ W1, const float* __restrict__ b1,
    const float* __restrict__ W2, float2* __restrict__ ps, int N) {
    __shared__ float sW1[256];
    __shared__ float sb1[64];
    __shared__ float sW2[128];
    int t = threadIdx.x;
    sW1[t] = W1[t];
    if (t < 64) sb1[t] = b1[t];
    if (t < 128) sW2[t] = W2[t];
    __syncthreads();
    int i = blockIdx.x * blockDim.x + t;
    if (i >= N) return;
    int is64 = detect64(ei);
    float di = dinv[i];
    float4 xv = x[i];
    float ax = xv.x * di, ay = xv.y * di, az = xv.z * di, aw = xv.w * di;
    int e = head[i];
    while (e >= 0) {
        int s = load_src(ei, e, is64);
        int en = next[e];
        float ds = dinv[s];
        float4 v = x[s];
        ax = fmaf(v.x, ds, ax);
        ay = fmaf(v.y, ds, ay);
        az = fmaf(v.z, ds, az);
        aw = fmaf(v.w, ds, aw);
        e = en;
    }
    ax *= di; ay *= di; az *= di; aw *= di;
    float p0 = 0.0f, p1 = 0.0f;
#pragma unroll
    for (int j = 0; j < 64; ++j) {
        float h = fmaf(ax, sW1[j],
                  fmaf(ay, sW1[64 + j],
                  fmaf(az, sW1[128 + j],
                  fmaf(aw, sW1[192 + j], sb1[j]))));
        h = fmaxf(h, 0.0f);
        p0 = fmaf(h, sW2[2 * j + 0], p0);
        p1 = fmaf(h, sW2[2 * j + 1], p1);
    }
    float2 r;
    r.x = p0 * di;
    r.y = p1 * di;
    ps[i] = r;
}

__global__ void walk_l2(const int* __restrict__ ei, int E,
                        const int* __restrict__ head, const int* __restrict__ next,
                        const float2* __restrict__ ps, const float* __restrict__ dinv,
                        const float* __restrict__ b2, float2* __restrict__ out, int N) {
    int i = blockIdx.x * blockDim.x + threadIdx.x;
    if (i >= N) return;
    int is64 = detect64(ei);
    float di = dinv[i];
    float2 acc = ps[i];
    int e = head[i];
    while (e >= 0) {
        int s = load_src(ei, e, is64);
        int en = next[e];
        float2 v = ps[s];
        acc.x += v.x;
        acc.y += v.y;
        e = en;
    }
    float2 r;
    r.x = fmaf(acc.x, di, b2[0]);
    r.y = fmaf(acc.y, di, b2[1]);
    out[i] = r;
}

// =====================================================================
extern "C" void kernel_launch(void* const* d_in, const int* in_sizes, int n_in,
                              void* d_out, int out_size, void* d_ws, size_t ws_size,
                              hipStream_t stream) {
    const float* x  = (const float*)d_in[0];
    const int*   ei = (const int*)d_in[1];
    const float* W1 = (const float*)d_in[2];
    const float* b1 = (const float*)d_in[3];
    const float* W2 = (const float*)d_in[4];
    const float* b2 = (const float*)d_in[5];

    const int N = in_sizes[0] / 4;
    const int E = in_sizes[1] / 2;

    const int eblocks = (E + THREADS - 1) / THREADS;
    const int nblocks = (N + THREADS - 1) / THREADS;

    char* ws = (char*)d_ws;
    const size_t needed = (size_t)N * 92 + 64;

    if (ws_size >= needed) {
        // ---- slot-CSR path ----
        int*          slots  = (int*)(ws);                                  // K*N ints
        unsigned int* cnt    = (unsigned int*)(ws + (size_t)N * 4 * K_SLOTS);
        float*        dinv   = (float*)(ws + (size_t)N * (4 * K_SLOTS + 4));
        int*          ovhead = (int*)(ws + (size_t)N * (4 * K_SLOTS + 8));
        int*          ovcnt  = (int*)(ws + (size_t)N * (4 * K_SLOTS + 12));
        int2*         pool   = (int2*)(ws + (size_t)N * (4 * K_SLOTS + 12) + 64);
        float4*       xs     = (float4*)(ws + (size_t)N * (4 * K_SLOTS + 20) + 64);
        float2*       ps     = (float2*)(ws + (size_t)N * (4 * K_SLOTS + 36) + 64);
        const int poolcap = N;  // 1M entries; expected overflow ~130K

        hipMemsetAsync(cnt, 0, (size_t)N * 4, stream);
        hipMemsetAsync(ovhead, 0xFF, (size_t)N * 4, stream);
        hipMemsetAsync(ovcnt, 0, 64, stream);

        build_slots<<<eblocks, THREADS, 0, stream>>>(ei, E, N, cnt, slots,
                                                     ovhead, ovcnt, pool, poolcap);
        node_prep<<<nblocks, THREADS, 0, stream>>>((const float4*)x, cnt, dinv, xs, N);
        slot_l1<<<nblocks, THREADS, 0, stream>>>(slots, cnt, ovhead, pool, xs, dinv,
                                                 W1, b1, W2, ps, N);
        slot_l2<<<nblocks, THREADS, 0, stream>>>(slots, cnt, ovhead, pool, ps, dinv,
                                                 b2, (float2*)d_out, N);
    } else {
        // ---- fallback: R2 linked-list path (48N bytes) ----
        int*   head = (int*)(ws);
        float* dinv = (float*)(ws + (size_t)N * 4);
        float* ps   = (float*)(ws + (size_t)N * 8);
        int*   next = (int*)(ws + (size_t)N * 16);

        hipMemsetAsync(head, 0xFF, (size_t)N * 4, stream);
        build_ll<<<eblocks, THREADS, 0, stream>>>(ei, E, head, next);
        walk_deg<<<nblocks, THREADS, 0, stream>>>(head, next, dinv, N);
        walk_l1<<<nblocks, THREADS, 0, stream>>>(ei, E, head, next, (const float4*)x,
                                                 dinv, W1, b1, W2, (float2*)ps, N);
        walk_l2<<<nblocks, THREADS, 0, stream>>>(ei, E, head, next, (const float2*)ps,
                                                 dinv, b2, (float2*)d_out, N);
    }
}

// Round 4
// 811.763 us; speedup vs baseline: 3.4283x; 1.4009x over previous
//
#include <hip/hip_runtime.h>

#define NBLK 1024        // blocks for edge-streaming passes
#define BTHREADS 256
#define BB 11            // bucket bits: 2048 nodes per bucket
#define BSZ (1 << BB)
#define BMASK (BSZ - 1)
#define MAXNB 512        // max buckets supported (N <= 1,048,576)
#define ATHREADS 1024    // threads for per-bucket aggregation kernels

// edge_index may arrive as int64 (little-endian, ids < 2^20 => odd dwords 0)
// or int32. Uniform per-thread check of the first 8 odd dwords.
__device__ __forceinline__ int detect64(const int* __restrict__ ei) {
    return (ei[1] | ei[3] | ei[5] | ei[7] | ei[9] | ei[11] | ei[13] | ei[15]) == 0;
}
__device__ __forceinline__ int load_src(const int* __restrict__ ei, int e, int is64) {
    return is64 ? ei[2 * (size_t)e] : ei[(size_t)e];
}
__device__ __forceinline__ int load_dst(const int* __restrict__ ei, int E, int e, int is64) {
    return is64 ? ei[2 * ((size_t)E + e)] : ei[(size_t)E + e];
}

// Pass 1: per-block histogram of dst buckets. No global atomics.
__global__ __launch_bounds__(BTHREADS) void pass1_hist(
    const int* __restrict__ ei, int E, int NB, unsigned int* __restrict__ off) {
    __shared__ unsigned int hist[MAXNB];
    int t = threadIdx.x, blk = blockIdx.x;
    for (int u = t; u < MAXNB; u += BTHREADS) hist[u] = 0;
    __syncthreads();
    int is64 = detect64(ei);
    int chunk = (E + NBLK - 1) / NBLK;
    int lo = blk * chunk;
    int hi = lo + chunk; if (hi > E) hi = E;
    for (int e = lo + t; e < hi; e += BTHREADS) {
        int d = load_dst(ei, E, e, is64);
        atomicAdd(&hist[d >> BB], 1u);
    }
    __syncthreads();
    for (int u = t; u < NB; u += BTHREADS) off[(size_t)u * NBLK + blk] = hist[u];
}

// Scan A: per bucket, exclusive scan over the 1024 per-block counts.
__global__ __launch_bounds__(BTHREADS) void scan_blocks(
    unsigned int* __restrict__ off, unsigned int* __restrict__ btot) {
    __shared__ unsigned int s[BTHREADS];
    int b = blockIdx.x, t = threadIdx.x;
    unsigned int* row = off + (size_t)b * NBLK;
    unsigned int v0 = row[4 * t], v1 = row[4 * t + 1], v2 = row[4 * t + 2], v3 = row[4 * t + 3];
    unsigned int sum = v0 + v1 + v2 + v3;
    s[t] = sum;
    __syncthreads();
    for (int o = 1; o < BTHREADS; o <<= 1) {
        unsigned int x = (t >= o) ? s[t - o] : 0;
        __syncthreads();
        s[t] += x;
        __syncthreads();
    }
    unsigned int base = t ? s[t - 1] : 0;
    row[4 * t] = base;
    row[4 * t + 1] = base + v0;
    row[4 * t + 2] = base + v0 + v1;
    row[4 * t + 3] = base + v0 + v1 + v2;
    if (t == BTHREADS - 1) btot[b] = s[BTHREADS - 1];
}

// Scan B: exclusive scan over bucket totals (NB <= 512, 2 per thread).
__global__ __launch_bounds__(BTHREADS) void scan_buckets(
    const unsigned int* __restrict__ btot, unsigned int* __restrict__ bbase, int NB) {
    __shared__ unsigned int s[BTHREADS];
    int t = threadIdx.x;
    unsigned int v0 = (2 * t < NB) ? btot[2 * t] : 0;
    unsigned int v1 = (2 * t + 1 < NB) ? btot[2 * t + 1] : 0;
    s[t] = v0 + v1;
    __syncthreads();
    for (int o = 1; o < BTHREADS; o <<= 1) {
        unsigned int x = (t >= o) ? s[t - o] : 0;
        __syncthreads();
        s[t] += x;
        __syncthreads();
    }
    unsigned int base = t ? s[t - 1] : 0;
    if (2 * t < NB) bbase[2 * t] = base;
    if (2 * t + 1 < NB) bbase[2 * t + 1] = base + v0;
}

// Pass 2: scatter packed records (src<<BB | dstlow) into bucket-contiguous ebin.
// LDS cursors only; no global atomics.
__global__ __launch_bounds__(BTHREADS) void pass2_scatter(
    const int* __restrict__ ei, int E, int NB,
    const unsigned int* __restrict__ off, const unsigned int* __restrict__ bbase,
    unsigned int* __restrict__ ebin) {
    __shared__ unsigned int cur[MAXNB];
    int t = threadIdx.x, blk = blockIdx.x;
    for (int u = t; u < NB; u += BTHREADS)
        cur[u] = bbase[u] + off[(size_t)u * NBLK + blk];
    __syncthreads();
    int is64 = detect64(ei);
    int chunk = (E + NBLK - 1) / NBLK;
    int lo = blk * chunk;
    int hi = lo + chunk; if (hi > E) hi = E;
    for (int e = lo + t; e < hi; e += BTHREADS) {
        int s = load_src(ei, e, is64);
        int d = load_dst(ei, E, e, is64);
        unsigned int pos = atomicAdd(&cur[d >> BB], 1u);
        ebin[pos] = ((unsigned int)s << BB) | (unsigned int)(d & BMASK);
    }
}

// Per bucket: degree histogram in LDS -> dinv, xs = x * dinv.
__global__ __launch_bounds__(ATHREADS) void deg_prep(
    const unsigned int* __restrict__ ebin, const unsigned int* __restrict__ bbase,
    const unsigned int* __restrict__ btot, const float4* __restrict__ x,
    float* __restrict__ dinv, float4* __restrict__ xs, int N) {
    __shared__ unsigned int dcnt[BSZ];
    int b = blockIdx.x, t = threadIdx.x;
    for (int j = t; j < BSZ; j += ATHREADS) dcnt[j] = 0;
    __syncthreads();
    unsigned int base = bbase[b];
    int cnt = (int)btot[b];
    for (int i = t; i < cnt; i += ATHREADS)
        atomicAdd(&dcnt[ebin[base + i] & BMASK], 1u);
    __syncthreads();
    int g0 = b << BB;
    int nn = N - g0; if (nn > BSZ) nn = BSZ;
    for (int j = t; j < nn; j += ATHREADS) {
        int g = g0 + j;
        float di = rsqrtf((float)(dcnt[j] + 1u));
        dinv[g] = di;
        float4 v = x[g];
        v.x *= di; v.y *= di; v.z *= di; v.w *= di;
        xs[g] = v;
    }
}

// Layer 1: gather xs[src], LDS f32 atomic accumulate, fused 4->64->2 MLP epilogue.
__global__ __launch_bounds__(ATHREADS) void l1_agg(
    const unsigned int* __restrict__ ebin, const unsigned int* __restrict__ bbase,
    const unsigned int* __restrict__ btot,
    const float4* __restrict__ xs, const float* __restrict__ dinv,
    const float* __restrict__ W1, const float* __restrict__ b1,
    const float* __restrict__ W2, float2* __restrict__ ps, int N) {
    __shared__ float acc[BSZ][4];   // 32 KB
    __shared__ float sW1[256];
    __shared__ float sb1[64];
    __shared__ float sW2[128];
    int b = blockIdx.x, t = threadIdx.x;
    if (t < 256) sW1[t] = W1[t];
    if (t < 64) sb1[t] = b1[t];
    if (t < 128) sW2[t] = W2[t];
    {
        float* p = &acc[0][0];
        for (int j = t; j < BSZ * 4; j += ATHREADS) p[j] = 0.0f;
    }
    __syncthreads();
    unsigned int base = bbase[b];
    int cnt = (int)btot[b];
    for (int i = t; i < cnt; i += ATHREADS) {
        unsigned int rec = ebin[base + i];
        int s = rec >> BB;
        int d = rec & BMASK;
        float4 v = xs[s];
        atomicAdd(&acc[d][0], v.x);
        atomicAdd(&acc[d][1], v.y);
        atomicAdd(&acc[d][2], v.z);
        atomicAdd(&acc[d][3], v.w);
    }
    __syncthreads();
    int g0 = b << BB;
    int nn = N - g0; if (nn > BSZ) nn = BSZ;
    for (int j = t; j < nn; j += ATHREADS) {
        int g = g0 + j;
        float di = dinv[g];
        float4 sv = xs[g];  // self-loop
        float ax = (acc[j][0] + sv.x) * di;
        float ay = (acc[j][1] + sv.y) * di;
        float az = (acc[j][2] + sv.z) * di;
        float aw = (acc[j][3] + sv.w) * di;
        float p0 = 0.0f, p1 = 0.0f;
#pragma unroll
        for (int k = 0; k < 64; ++k) {
            float h = fmaf(ax, sW1[k],
                      fmaf(ay, sW1[64 + k],
                      fmaf(az, sW1[128 + k],
                      fmaf(aw, sW1[192 + k], sb1[k]))));
            h = fmaxf(h, 0.0f);
            p0 = fmaf(h, sW2[2 * k + 0], p0);
            p1 = fmaf(h, sW2[2 * k + 1], p1);
        }
        float2 r;
        r.x = p0 * di;
        r.y = p1 * di;
        ps[g] = r;
    }
}

// Layer 2: gather ps[src], LDS accumulate, epilogue -> out.
__global__ __launch_bounds__(ATHREADS) void l2_agg(
    const unsigned int* __restrict__ ebin, const unsigned int* __restrict__ bbase,
    const unsigned int* __restrict__ btot,
    const float2* __restrict__ ps, const float* __restrict__ dinv,
    const float* __restrict__ b2, float2* __restrict__ out, int N) {
    __shared__ float acc[BSZ][2];   // 16 KB
    int b = blockIdx.x, t = threadIdx.x;
    {
        float* p = &acc[0][0];
        for (int j = t; j < BSZ * 2; j += ATHREADS) p[j] = 0.0f;
    }
    __syncthreads();
    unsigned int base = bbase[b];
    int cnt = (int)btot[b];
    for (int i = t; i < cnt; i += ATHREADS) {
        unsigned int rec = ebin[base + i];
        int s = rec >> BB;
        int d = rec & BMASK;
        float2 v = ps[s];
        atomicAdd(&acc[d][0], v.x);
        atomicAdd(&acc[d][1], v.y);
    }
    __syncthreads();
    int g0 = b << BB;
    int nn = N - g0; if (nn > BSZ) nn = BSZ;
    float c0 = b2[0], c1 = b2[1];
    for (int j = t; j < nn; j += ATHREADS) {
        int g = g0 + j;
        float di = dinv[g];
        float2 sv = ps[g];  // self-loop
        float2 r;
        r.x = fmaf(acc[j][0] + sv.x, di, c0);
        r.y = fmaf(acc[j][1] + sv.y, di, c1);
        out[g] = r;
    }
}

static inline size_t align256(size_t v) { return (v + 255) & ~(size_t)255; }

extern "C" void kernel_launch(void* const* d_in, const int* in_sizes, int n_in,
                              void* d_out, int out_size, void* d_ws, size_t ws_size,
                              hipStream_t stream) {
    const float* x  = (const float*)d_in[0];
    const int*   ei = (const int*)d_in[1];
    const float* W1 = (const float*)d_in[2];
    const float* b1 = (const float*)d_in[3];
    const float* W2 = (const float*)d_in[4];
    const float* b2 = (const float*)d_in[5];

    const int N = in_sizes[0] / 4;
    const int E = in_sizes[1] / 2;
    const int NB = (N + BSZ - 1) >> BB;   // buckets (<= MAXNB for N <= 1M)

    // Workspace layout (all 256B-aligned):
    char* ws = (char*)d_ws;
    size_t o = 0;
    unsigned int* ebin  = (unsigned int*)(ws + o); o = align256(o + (size_t)E * 4);
    unsigned int* off   = (unsigned int*)(ws + o); o = align256(o + (size_t)MAXNB * NBLK * 4);
    unsigned int* btot  = (unsigned int*)(ws + o); o = align256(o + (size_t)MAXNB * 4);
    unsigned int* bbase = (unsigned int*)(ws + o); o = align256(o + (size_t)MAXNB * 4);
    float*        dinv  = (float*)(ws + o);        o = align256(o + (size_t)N * 4);
    float4*       xs    = (float4*)(ws + o);       o = align256(o + (size_t)N * 16);
    float2*       ps    = (float2*)(ws + o);       o = align256(o + (size_t)N * 8);

    pass1_hist<<<NBLK, BTHREADS, 0, stream>>>(ei, E, NB, off);
    scan_blocks<<<NB, BTHREADS, 0, stream>>>(off, btot);
    scan_buckets<<<1, BTHREADS, 0, stream>>>(btot, bbase, NB);
    pass2_scatter<<<NBLK, BTHREADS, 0, stream>>>(ei, E, NB, off, bbase, ebin);
    deg_prep<<<NB, ATHREADS, 0, stream>>>(ebin, bbase, btot, (const float4*)x, dinv, xs, N);
    l1_agg<<<NB, ATHREADS, 0, stream>>>(ebin, bbase, btot, xs, dinv, W1, b1, W2, ps, N);
    l2_agg<<<NB, ATHREADS, 0, stream>>>(ebin, bbase, btot, ps, dinv, b2, (float2*)d_out, N);
}

// Round 5
// 625.994 us; speedup vs baseline: 4.4457x; 1.2968x over previous
//
#include <hip/hip_runtime.h>
#include <hip/hip_fp16.h>

#define NBLK 1024        // blocks for edge-streaming passes
#define BTHREADS 256
#define BB 11            // bucket bits: 2048 nodes per bucket
#define BSZ (1 << BB)
#define BMASK (BSZ - 1)
#define MAXNB 512        // max buckets supported (N <= 1,048,576)
#define ATHREADS 512     // threads for per-bucket aggregation kernels (100% occ)

// ---------------- helpers ----------------
__device__ __forceinline__ int detect64(const int* __restrict__ ei) {
    return (ei[1] | ei[3] | ei[5] | ei[7] | ei[9] | ei[11] | ei[13] | ei[15]) == 0;
}
__device__ __forceinline__ int load_src(const int* __restrict__ ei, int e, int is64) {
    return is64 ? ei[2 * (size_t)e] : ei[(size_t)e];
}
__device__ __forceinline__ int load_dst(const int* __restrict__ ei, int E, int e, int is64) {
    return is64 ? ei[2 * ((size_t)E + e)] : ei[(size_t)E + e];
}
__device__ __forceinline__ unsigned int h2u(__half2 h) {
    union { __half2 h; unsigned int u; } c; c.h = h; return c.u;
}
__device__ __forceinline__ __half2 u2h(unsigned int u) {
    union { __half2 h; unsigned int u; } c; c.u = u; return c.h;
}

// Pass 1: per-block histogram of dst buckets. No global atomics.
__global__ __launch_bounds__(BTHREADS) void pass1_hist(
    const int* __restrict__ ei, int E, int NB, unsigned int* __restrict__ off) {
    __shared__ unsigned int hist[MAXNB];
    int t = threadIdx.x, blk = blockIdx.x;
    for (int u = t; u < MAXNB; u += BTHREADS) hist[u] = 0;
    __syncthreads();
    int is64 = detect64(ei);
    int chunk = (E + NBLK - 1) / NBLK;
    int lo = blk * chunk;
    int hi = lo + chunk; if (hi > E) hi = E;
    for (int e = lo + t; e < hi; e += BTHREADS) {
        int d = load_dst(ei, E, e, is64);
        atomicAdd(&hist[d >> BB], 1u);
    }
    __syncthreads();
    for (int u = t; u < NB; u += BTHREADS) off[(size_t)u * NBLK + blk] = hist[u];
}

// Scan A: per bucket, exclusive scan over the 1024 per-block counts.
__global__ __launch_bounds__(BTHREADS) void scan_blocks(
    unsigned int* __restrict__ off, unsigned int* __restrict__ btot) {
    __shared__ unsigned int s[BTHREADS];
    int b = blockIdx.x, t = threadIdx.x;
    unsigned int* row = off + (size_t)b * NBLK;
    unsigned int v0 = row[4 * t], v1 = row[4 * t + 1], v2 = row[4 * t + 2], v3 = row[4 * t + 3];
    unsigned int sum = v0 + v1 + v2 + v3;
    s[t] = sum;
    __syncthreads();
    for (int o = 1; o < BTHREADS; o <<= 1) {
        unsigned int x = (t >= o) ? s[t - o] : 0;
        __syncthreads();
        s[t] += x;
        __syncthreads();
    }
    unsigned int base = t ? s[t - 1] : 0;
    row[4 * t] = base;
    row[4 * t + 1] = base + v0;
    row[4 * t + 2] = base + v0 + v1;
    row[4 * t + 3] = base + v0 + v1 + v2;
    if (t == BTHREADS - 1) btot[b] = s[BTHREADS - 1];
}

// Scan B: exclusive scan over bucket totals (NB <= 512).
__global__ __launch_bounds__(BTHREADS) void scan_buckets(
    const unsigned int* __restrict__ btot, unsigned int* __restrict__ bbase, int NB) {
    __shared__ unsigned int s[BTHREADS];
    int t = threadIdx.x;
    unsigned int v0 = (2 * t < NB) ? btot[2 * t] : 0;
    unsigned int v1 = (2 * t + 1 < NB) ? btot[2 * t + 1] : 0;
    s[t] = v0 + v1;
    __syncthreads();
    for (int o = 1; o < BTHREADS; o <<= 1) {
        unsigned int x = (t >= o) ? s[t - o] : 0;
        __syncthreads();
        s[t] += x;
        __syncthreads();
    }
    unsigned int base = t ? s[t - 1] : 0;
    if (2 * t < NB) bbase[2 * t] = base;
    if (2 * t + 1 < NB) bbase[2 * t + 1] = base + v0;
}

// Pass 2: scatter packed records (src<<BB | dstlow) into bucket-contiguous ebin.
__global__ __launch_bounds__(BTHREADS) void pass2_scatter(
    const int* __restrict__ ei, int E, int NB,
    const unsigned int* __restrict__ off, const unsigned int* __restrict__ bbase,
    unsigned int* __restrict__ ebin) {
    __shared__ unsigned int cur[MAXNB];
    int t = threadIdx.x, blk = blockIdx.x;
    for (int u = t; u < NB; u += BTHREADS)
        cur[u] = bbase[u] + off[(size_t)u * NBLK + blk];
    __syncthreads();
    int is64 = detect64(ei);
    int chunk = (E + NBLK - 1) / NBLK;
    int lo = blk * chunk;
    int hi = lo + chunk; if (hi > E) hi = E;
    for (int e = lo + t; e < hi; e += BTHREADS) {
        int s = load_src(ei, e, is64);
        int d = load_dst(ei, E, e, is64);
        unsigned int pos = atomicAdd(&cur[d >> BB], 1u);
        ebin[pos] = ((unsigned int)s << BB) | (unsigned int)(d & BMASK);
    }
}

// Per bucket: degree histogram in LDS -> dinv (f32), xs = half4(x * dinv) (uint2).
__global__ __launch_bounds__(ATHREADS) void deg_prep(
    const unsigned int* __restrict__ ebin, const unsigned int* __restrict__ bbase,
    const unsigned int* __restrict__ btot, const float4* __restrict__ x,
    float* __restrict__ dinv, uint2* __restrict__ xs, int N) {
    __shared__ unsigned int dcnt[BSZ];
    int b = blockIdx.x, t = threadIdx.x;
    for (int j = t; j < BSZ; j += ATHREADS) dcnt[j] = 0;
    __syncthreads();
    unsigned int base = bbase[b];
    int cnt = (int)btot[b];
    for (int i = t; i < cnt; i += ATHREADS)
        atomicAdd(&dcnt[ebin[base + i] & BMASK], 1u);
    __syncthreads();
    int g0 = b << BB;
    int nn = N - g0; if (nn > BSZ) nn = BSZ;
    for (int j = t; j < nn; j += ATHREADS) {
        int g = g0 + j;
        float di = rsqrtf((float)(dcnt[j] + 1u));
        dinv[g] = di;
        float4 v = x[g];
        uint2 p;
        p.x = h2u(__halves2half2(__float2half_rn(v.x * di), __float2half_rn(v.y * di)));
        p.y = h2u(__halves2half2(__float2half_rn(v.z * di), __float2half_rn(v.w * di)));
        xs[g] = p;
    }
}

// Layer 1: gather half4 xs[src], LDS f32 accumulate, fused 4->64->2 MLP epilogue.
// Output ps = half2(p * dinv) packed in uint.
__global__ __launch_bounds__(ATHREADS) void l1_agg(
    const unsigned int* __restrict__ ebin, const unsigned int* __restrict__ bbase,
    const unsigned int* __restrict__ btot,
    const uint2* __restrict__ xs, const float* __restrict__ dinv,
    const float* __restrict__ W1, const float* __restrict__ b1,
    const float* __restrict__ W2, unsigned int* __restrict__ ps, int N) {
    __shared__ float acc[BSZ][4];   // 32 KB
    __shared__ float sW1[256];
    __shared__ float sb1[64];
    __shared__ float sW2[128];
    int b = blockIdx.x, t = threadIdx.x;
    if (t < 256) sW1[t] = W1[t];
    if (t < 64) sb1[t] = b1[t];
    if (t < 128) sW2[t] = W2[t];
    {
        float* p = &acc[0][0];
        for (int j = t; j < BSZ * 4; j += ATHREADS) p[j] = 0.0f;
    }
    __syncthreads();
    unsigned int base = bbase[b];
    int cnt = (int)btot[b];
    for (int i = t; i < cnt; i += ATHREADS) {
        unsigned int rec = ebin[base + i];
        int s = rec >> BB;
        int d = rec & BMASK;
        uint2 raw = xs[s];
        __half2 h01 = u2h(raw.x), h23 = u2h(raw.y);
        atomicAdd(&acc[d][0], __half2float(__low2half(h01)));
        atomicAdd(&acc[d][1], __half2float(__high2half(h01)));
        atomicAdd(&acc[d][2], __half2float(__low2half(h23)));
        atomicAdd(&acc[d][3], __half2float(__high2half(h23)));
    }
    __syncthreads();
    int g0 = b << BB;
    int nn = N - g0; if (nn > BSZ) nn = BSZ;
    for (int j = t; j < nn; j += ATHREADS) {
        int g = g0 + j;
        float di = dinv[g];
        uint2 raw = xs[g];  // self-loop (quantized, consistent)
        __half2 h01 = u2h(raw.x), h23 = u2h(raw.y);
        float ax = (acc[j][0] + __half2float(__low2half(h01))) * di;
        float ay = (acc[j][1] + __half2float(__high2half(h01))) * di;
        float az = (acc[j][2] + __half2float(__low2half(h23))) * di;
        float aw = (acc[j][3] + __half2float(__high2half(h23))) * di;
        float p0 = 0.0f, p1 = 0.0f;
#pragma unroll
        for (int k = 0; k < 64; ++k) {
            float h = fmaf(ax, sW1[k],
                      fmaf(ay, sW1[64 + k],
                      fmaf(az, sW1[128 + k],
                      fmaf(aw, sW1[192 + k], sb1[k]))));
            h = fmaxf(h, 0.0f);
            p0 = fmaf(h, sW2[2 * k + 0], p0);
            p1 = fmaf(h, sW2[2 * k + 1], p1);
        }
        ps[g] = h2u(__halves2half2(__float2half_rn(p0 * di), __float2half_rn(p1 * di)));
    }
}

// Layer 2: gather half2 ps[src] (4 MB table, L2-resident), LDS accumulate, epilogue.
__global__ __launch_bounds__(ATHREADS) void l2_agg(
    const unsigned int* __restrict__ ebin, const unsigned int* __restrict__ bbase,
    const unsigned int* __restrict__ btot,
    const unsigned int* __restrict__ ps, const float* __restrict__ dinv,
    const float* __restrict__ b2, float2* __restrict__ out, int N) {
    __shared__ float acc[BSZ][2];   // 16 KB
    int b = blockIdx.x, t = threadIdx.x;
    {
        float* p = &acc[0][0];
        for (int j = t; j < BSZ * 2; j += ATHREADS) p[j] = 0.0f;
    }
    __syncthreads();
    unsigned int base = bbase[b];
    int cnt = (int)btot[b];
    for (int i = t; i < cnt; i += ATHREADS) {
        unsigned int rec = ebin[base + i];
        int s = rec >> BB;
        int d = rec & BMASK;
        __half2 h = u2h(ps[s]);
        atomicAdd(&acc[d][0], __half2float(__low2half(h)));
        atomicAdd(&acc[d][1], __half2float(__high2half(h)));
    }
    __syncthreads();
    int g0 = b << BB;
    int nn = N - g0; if (nn > BSZ) nn = BSZ;
    float c0 = b2[0], c1 = b2[1];
    for (int j = t; j < nn; j += ATHREADS) {
        int g = g0 + j;
        float di = dinv[g];
        __half2 h = u2h(ps[g]);  // self-loop
        float2 r;
        r.x = fmaf(acc[j][0] + __half2float(__low2half(h)), di, c0);
        r.y = fmaf(acc[j][1] + __half2float(__high2half(h)), di, c1);
        out[g] = r;
    }
}

static inline size_t align256(size_t v) { return (v + 255) & ~(size_t)255; }

extern "C" void kernel_launch(void* const* d_in, const int* in_sizes, int n_in,
                              void* d_out, int out_size, void* d_ws, size_t ws_size,
                              hipStream_t stream) {
    const float* x  = (const float*)d_in[0];
    const int*   ei = (const int*)d_in[1];
    const float* W1 = (const float*)d_in[2];
    const float* b1 = (const float*)d_in[3];
    const float* W2 = (const float*)d_in[4];
    const float* b2 = (const float*)d_in[5];

    const int N = in_sizes[0] / 4;
    const int E = in_sizes[1] / 2;
    const int NB = (N + BSZ - 1) >> BB;

    char* ws = (char*)d_ws;
    size_t o = 0;
    unsigned int* ebin  = (unsigned int*)(ws + o); o = align256(o + (size_t)E * 4);
    unsigned int* off   = (unsigned int*)(ws + o); o = align256(o + (size_t)MAXNB * NBLK * 4);
    unsigned int* btot  = (unsigned int*)(ws + o); o = align256(o + (size_t)MAXNB * 4);
    unsigned int* bbase = (unsigned int*)(ws + o); o = align256(o + (size_t)MAXNB * 4);
    float*        dinv  = (float*)(ws + o);        o = align256(o + (size_t)N * 4);
    uint2*        xs    = (uint2*)(ws + o);        o = align256(o + (size_t)N * 8);
    unsigned int* ps    = (unsigned int*)(ws + o); o = align256(o + (size_t)N * 4);

    pass1_hist<<<NBLK, BTHREADS, 0, stream>>>(ei, E, NB, off);
    scan_blocks<<<NB, BTHREADS, 0, stream>>>(off, btot);
    scan_buckets<<<1, BTHREADS, 0, stream>>>(btot, bbase, NB);
    pass2_scatter<<<NBLK, BTHREADS, 0, stream>>>(ei, E, NB, off, bbase, ebin);
    deg_prep<<<NB, ATHREADS, 0, stream>>>(ebin, bbase, btot, (const float4*)x, dinv, xs, N);
    l1_agg<<<NB, ATHREADS, 0, stream>>>(ebin, bbase, btot, xs, dinv, W1, b1, W2, ps, N);
    l2_agg<<<NB, ATHREADS, 0, stream>>>(ebin, bbase, btot, ps, dinv, b2, (float2*)d_out, N);
}

// Round 6
// 584.931 us; speedup vs baseline: 4.7577x; 1.0702x over previous
//
#include <hip/hip_runtime.h>
#include <hip/hip_fp16.h>

#define NBLK 1024        // blocks for edge-streaming passes
#define BTHREADS 256
#define BB 11            // bucket bits: 2048 nodes per bucket
#define BSZ (1 << BB)
#define BMASK (BSZ - 1)
#define MAXNB 512        // max buckets supported (N <= 1,048,576)
#define GTHREADS 512     // gather/accumulate kernels

// ---------------- helpers ----------------
__device__ __forceinline__ int detect64(const int* __restrict__ ei) {
    return (ei[1] | ei[3] | ei[5] | ei[7] | ei[9] | ei[11] | ei[13] | ei[15]) == 0;
}
__device__ __forceinline__ int load_src(const int* __restrict__ ei, int e, int is64) {
    return is64 ? ei[2 * (size_t)e] : ei[(size_t)e];
}
__device__ __forceinline__ int load_dst(const int* __restrict__ ei, int E, int e, int is64) {
    return is64 ? ei[2 * ((size_t)E + e)] : ei[(size_t)E + e];
}
__device__ __forceinline__ unsigned int h2u(__half2 h) {
    union { __half2 h; unsigned int u; } c; c.h = h; return c.u;
}
__device__ __forceinline__ __half2 u2h(unsigned int u) {
    union { __half2 h; unsigned int u; } c; c.u = u; return c.h;
}

// Pass 1: per-block histogram of dst buckets. No global atomics.
__global__ __launch_bounds__(BTHREADS) void pass1_hist(
    const int* __restrict__ ei, int E, int NB, unsigned int* __restrict__ off) {
    __shared__ unsigned int hist[MAXNB];
    int t = threadIdx.x, blk = blockIdx.x;
    for (int u = t; u < MAXNB; u += BTHREADS) hist[u] = 0;
    __syncthreads();
    int is64 = detect64(ei);
    int chunk = (E + NBLK - 1) / NBLK;
    int lo = blk * chunk;
    int hi = lo + chunk; if (hi > E) hi = E;
    for (int e = lo + t; e < hi; e += BTHREADS) {
        int d = load_dst(ei, E, e, is64);
        atomicAdd(&hist[d >> BB], 1u);
    }
    __syncthreads();
    for (int u = t; u < NB; u += BTHREADS) off[(size_t)u * NBLK + blk] = hist[u];
}

// Scan A: per bucket, exclusive scan over the 1024 per-block counts.
__global__ __launch_bounds__(BTHREADS) void scan_blocks(
    unsigned int* __restrict__ off, unsigned int* __restrict__ btot) {
    __shared__ unsigned int s[BTHREADS];
    int b = blockIdx.x, t = threadIdx.x;
    unsigned int* row = off + (size_t)b * NBLK;
    unsigned int v0 = row[4 * t], v1 = row[4 * t + 1], v2 = row[4 * t + 2], v3 = row[4 * t + 3];
    unsigned int sum = v0 + v1 + v2 + v3;
    s[t] = sum;
    __syncthreads();
    for (int o = 1; o < BTHREADS; o <<= 1) {
        unsigned int x = (t >= o) ? s[t - o] : 0;
        __syncthreads();
        s[t] += x;
        __syncthreads();
    }
    unsigned int base = t ? s[t - 1] : 0;
    row[4 * t] = base;
    row[4 * t + 1] = base + v0;
    row[4 * t + 2] = base + v0 + v1;
    row[4 * t + 3] = base + v0 + v1 + v2;
    if (t == BTHREADS - 1) btot[b] = s[BTHREADS - 1];
}

// Scan B: exclusive scan over bucket totals (NB <= 512).
__global__ __launch_bounds__(BTHREADS) void scan_buckets(
    const unsigned int* __restrict__ btot, unsigned int* __restrict__ bbase, int NB) {
    __shared__ unsigned int s[BTHREADS];
    int t = threadIdx.x;
    unsigned int v0 = (2 * t < NB) ? btot[2 * t] : 0;
    unsigned int v1 = (2 * t + 1 < NB) ? btot[2 * t + 1] : 0;
    s[t] = v0 + v1;
    __syncthreads();
    for (int o = 1; o < BTHREADS; o <<= 1) {
        unsigned int x = (t >= o) ? s[t - o] : 0;
        __syncthreads();
        s[t] += x;
        __syncthreads();
    }
    unsigned int base = t ? s[t - 1] : 0;
    if (2 * t < NB) bbase[2 * t] = base;
    if (2 * t + 1 < NB) bbase[2 * t + 1] = base + v0;
}

// Pass 2: scatter packed records (src<<BB | dstlow) into bucket-contiguous ebin.
__global__ __launch_bounds__(BTHREADS) void pass2_scatter(
    const int* __restrict__ ei, int E, int NB,
    const unsigned int* __restrict__ off, const unsigned int* __restrict__ bbase,
    unsigned int* __restrict__ ebin) {
    __shared__ unsigned int cur[MAXNB];
    int t = threadIdx.x, blk = blockIdx.x;
    for (int u = t; u < NB; u += BTHREADS)
        cur[u] = bbase[u] + off[(size_t)u * NBLK + blk];
    __syncthreads();
    int is64 = detect64(ei);
    int chunk = (E + NBLK - 1) / NBLK;
    int lo = blk * chunk;
    int hi = lo + chunk; if (hi > E) hi = E;
    for (int e = lo + t; e < hi; e += BTHREADS) {
        int s = load_src(ei, e, is64);
        int d = load_dst(ei, E, e, is64);
        unsigned int pos = atomicAdd(&cur[d >> BB], 1u);
        ebin[pos] = ((unsigned int)s << BB) | (unsigned int)(d & BMASK);
    }
}

// Per bucket: degree histogram in LDS -> dinv (f32), xs = half4(x * dinv) (uint2).
__global__ __launch_bounds__(GTHREADS) void deg_prep(
    const unsigned int* __restrict__ ebin, const unsigned int* __restrict__ bbase,
    const unsigned int* __restrict__ btot, const float4* __restrict__ x,
    float* __restrict__ dinv, uint2* __restrict__ xs, int N) {
    __shared__ unsigned int dcnt[BSZ];
    int b = blockIdx.x, t = threadIdx.x;
    for (int j = t; j < BSZ; j += GTHREADS) dcnt[j] = 0;
    __syncthreads();
    unsigned int base = bbase[b];
    int cnt = (int)btot[b];
    for (int i = t; i < cnt; i += GTHREADS)
        atomicAdd(&dcnt[ebin[base + i] & BMASK], 1u);
    __syncthreads();
    int g0 = b << BB;
    int nn = N - g0; if (nn > BSZ) nn = BSZ;
    for (int j = t; j < nn; j += GTHREADS) {
        int g = g0 + j;
        float di = rsqrtf((float)(dcnt[j] + 1u));
        dinv[g] = di;
        float4 v = x[g];
        uint2 p;
        p.x = h2u(__halves2half2(__float2half_rn(v.x * di), __float2half_rn(v.y * di)));
        p.y = h2u(__halves2half2(__float2half_rn(v.z * di), __float2half_rn(v.w * di)));
        xs[g] = p;
    }
}

// Layer-1 gather/accumulate ONLY: low-VGPR, 100%-occupancy, 4-deep ILP.
// Dumps raw neighbor sums (no self-loop) to agg[].
__global__ __launch_bounds__(GTHREADS, 8) void l1_gather(
    const unsigned int* __restrict__ ebin, const unsigned int* __restrict__ bbase,
    const unsigned int* __restrict__ btot,
    const uint2* __restrict__ xs, float4* __restrict__ agg, int N) {
    __shared__ float acc[BSZ][4];   // 32 KB
    int b = blockIdx.x, t = threadIdx.x;
    {
        float* p = &acc[0][0];
        for (int j = t; j < BSZ * 4; j += GTHREADS) p[j] = 0.0f;
    }
    __syncthreads();
    unsigned int base = bbase[b];
    int cnt = (int)btot[b];
    for (int i0 = 4 * t; i0 < cnt; i0 += 4 * GTHREADS) {
        int m = cnt - i0; if (m > 4) m = 4;
        unsigned int rec[4];
        uint2 raw[4];
#pragma unroll
        for (int j = 0; j < 4; ++j) if (j < m) rec[j] = ebin[base + i0 + j];
#pragma unroll
        for (int j = 0; j < 4; ++j) if (j < m) raw[j] = xs[rec[j] >> BB];
#pragma unroll
        for (int j = 0; j < 4; ++j) if (j < m) {
            int d = rec[j] & BMASK;
            __half2 h01 = u2h(raw[j].x), h23 = u2h(raw[j].y);
            atomicAdd(&acc[d][0], __half2float(__low2half(h01)));
            atomicAdd(&acc[d][1], __half2float(__high2half(h01)));
            atomicAdd(&acc[d][2], __half2float(__low2half(h23)));
            atomicAdd(&acc[d][3], __half2float(__high2half(h23)));
        }
    }
    __syncthreads();
    int g0 = b << BB;
    int nn = N - g0; if (nn > BSZ) nn = BSZ;
    for (int j = t; j < nn; j += GTHREADS)
        agg[g0 + j] = make_float4(acc[j][0], acc[j][1], acc[j][2], acc[j][3]);
}

// Layer-1 MLP epilogue: streaming, register-fat is fine here.
__global__ __launch_bounds__(256) void l1_mlp(
    const float4* __restrict__ agg, const uint2* __restrict__ xs,
    const float* __restrict__ dinv,
    const float* __restrict__ W1, const float* __restrict__ b1,
    const float* __restrict__ W2, unsigned int* __restrict__ ps, int N) {
    __shared__ float sW1[256];
    __shared__ float sb1[64];
    __shared__ float sW2[128];
    int t = threadIdx.x;
    sW1[t] = W1[t];
    if (t < 64) sb1[t] = b1[t];
    if (t < 128) sW2[t] = W2[t];
    __syncthreads();
    int i = blockIdx.x * 256 + t;
    if (i >= N) return;
    float di = dinv[i];
    float4 a = agg[i];
    uint2 raw = xs[i];  // self-loop (quantized, consistent)
    __half2 h01 = u2h(raw.x), h23 = u2h(raw.y);
    float ax = (a.x + __half2float(__low2half(h01))) * di;
    float ay = (a.y + __half2float(__high2half(h01))) * di;
    float az = (a.z + __half2float(__low2half(h23))) * di;
    float aw = (a.w + __half2float(__high2half(h23))) * di;
    float p0 = 0.0f, p1 = 0.0f;
#pragma unroll
    for (int k = 0; k < 64; ++k) {
        float h = fmaf(ax, sW1[k],
                  fmaf(ay, sW1[64 + k],
                  fmaf(az, sW1[128 + k],
                  fmaf(aw, sW1[192 + k], sb1[k]))));
        h = fmaxf(h, 0.0f);
        p0 = fmaf(h, sW2[2 * k + 0], p0);
        p1 = fmaf(h, sW2[2 * k + 1], p1);
    }
    ps[i] = h2u(__halves2half2(__float2half_rn(p0 * di), __float2half_rn(p1 * di)));
}

// Layer 2: gather half2 ps[src] (4 MB table), LDS accumulate, epilogue. 4-deep ILP.
__global__ __launch_bounds__(GTHREADS, 8) void l2_agg(
    const unsigned int* __restrict__ ebin, const unsigned int* __restrict__ bbase,
    const unsigned int* __restrict__ btot,
    const unsigned int* __restrict__ ps, const float* __restrict__ dinv,
    const float* __restrict__ b2, float2* __restrict__ out, int N) {
    __shared__ float acc[BSZ][2];   // 16 KB
    int b = blockIdx.x, t = threadIdx.x;
    {
        float* p = &acc[0][0];
        for (int j = t; j < BSZ * 2; j += GTHREADS) p[j] = 0.0f;
    }
    __syncthreads();
    unsigned int base = bbase[b];
    int cnt = (int)btot[b];
    for (int i0 = 4 * t; i0 < cnt; i0 += 4 * GTHREADS) {
        int m = cnt - i0; if (m > 4) m = 4;
        unsigned int rec[4];
        unsigned int raw[4];
#pragma unroll
        for (int j = 0; j < 4; ++j) if (j < m) rec[j] = ebin[base + i0 + j];
#pragma unroll
        for (int j = 0; j < 4; ++j) if (j < m) raw[j] = ps[rec[j] >> BB];
#pragma unroll
        for (int j = 0; j < 4; ++j) if (j < m) {
            int d = rec[j] & BMASK;
            __half2 h = u2h(raw[j]);
            atomicAdd(&acc[d][0], __half2float(__low2half(h)));
            atomicAdd(&acc[d][1], __half2float(__high2half(h)));
        }
    }
    __syncthreads();
    int g0 = b << BB;
    int nn = N - g0; if (nn > BSZ) nn = BSZ;
    float c0 = b2[0], c1 = b2[1];
    for (int j = t; j < nn; j += GTHREADS) {
        int g = g0 + j;
        float di = dinv[g];
        __half2 h = u2h(ps[g]);  // self-loop
        float2 r;
        r.x = fmaf(acc[j][0] + __half2float(__low2half(h)), di, c0);
        r.y = fmaf(acc[j][1] + __half2float(__high2half(h)), di, c1);
        out[g] = r;
    }
}

static inline size_t align256(size_t v) { return (v + 255) & ~(size_t)255; }

extern "C" void kernel_launch(void* const* d_in, const int* in_sizes, int n_in,
                              void* d_out, int out_size, void* d_ws, size_t ws_size,
                              hipStream_t stream) {
    const float* x  = (const float*)d_in[0];
    const int*   ei = (const int*)d_in[1];
    const float* W1 = (const float*)d_in[2];
    const float* b1 = (const float*)d_in[3];
    const float* W2 = (const float*)d_in[4];
    const float* b2 = (const float*)d_in[5];

    const int N = in_sizes[0] / 4;
    const int E = in_sizes[1] / 2;
    const int NB = (N + BSZ - 1) >> BB;

    char* ws = (char*)d_ws;
    size_t o = 0;
    unsigned int* ebin  = (unsigned int*)(ws + o); o = align256(o + (size_t)E * 4);
    unsigned int* off   = (unsigned int*)(ws + o); o = align256(o + (size_t)MAXNB * NBLK * 4);
    unsigned int* btot  = (unsigned int*)(ws + o); o = align256(o + (size_t)MAXNB * 4);
    unsigned int* bbase = (unsigned int*)(ws + o); o = align256(o + (size_t)MAXNB * 4);
    float*        dinv  = (float*)(ws + o);        o = align256(o + (size_t)N * 4);
    uint2*        xs    = (uint2*)(ws + o);        o = align256(o + (size_t)N * 8);
    unsigned int* ps    = (unsigned int*)(ws + o); o = align256(o + (size_t)N * 4);
    float4*       agg   = (float4*)(ws + o);       o = align256(o + (size_t)N * 16);

    pass1_hist<<<NBLK, BTHREADS, 0, stream>>>(ei, E, NB, off);
    scan_blocks<<<NB, BTHREADS, 0, stream>>>(off, btot);
    scan_buckets<<<1, BTHREADS, 0, stream>>>(btot, bbase, NB);
    pass2_scatter<<<NBLK, BTHREADS, 0, stream>>>(ei, E, NB, off, bbase, ebin);
    deg_prep<<<NB, GTHREADS, 0, stream>>>(ebin, bbase, btot, (const float4*)x, dinv, xs, N);
    l1_gather<<<NB, GTHREADS, 0, stream>>>(ebin, bbase, btot, xs, agg, N);
    l1_mlp<<<(N + 255) / 256, 256, 0, stream>>>(agg, xs, dinv, W1, b1, W2, ps, N);
    l2_agg<<<NB, GTHREADS, 0, stream>>>(ebin, bbase, btot, ps, dinv, b2, (float2*)d_out, N);
}